// Round 5
// baseline (82.505 us; speedup 1.0000x reference)
//
#include <hip/hip_runtime.h>

// Linear attention, fp32. N=8, L=S=8192, H=8, D=Dv=32.
// out[n,l,h,v] = (sum_d phiQ[l,d]*KV[d][v]) * 1/(sum_d phiQ[l,d]*Ksum[d] + 1e-6)
// where KV[d][v] = sum_s phiK[s,d]*values[s,v]  (the /S and *S of the reference
// cancel exactly: S is a power of two).
//
// R5: phase2 writes made DENSE. R1-R4 all ~63-70us regardless of compute
// structure; the invariant was the store pattern (128B per 1KB stride,
// h-split across blocks) -> ~1.0 TB/s effective write BW = the entire dur.
// Now each block owns 32 consecutive (n,l) rows x ALL 8 heads: every
// wave-store is 1KB contiguous, block writes 32KB sequential. KV[h] slice +
// Ksum[h] in VGPRs; Q via LDS transpose (conflict-free both sides).

#define N_      8
#define L_      8192
#define S_      8192
#define H_      8
#define D_      32
#define NH_     64            // N*H
#define CHUNKS_ 32            // s-chunks per (n,h) in phase 1
#define ROWS_   (S_ / CHUNKS_) // 256 rows per block
#define TILE_   64            // staged rows per LDS tile
#define KVE_    (D_ * D_)     // 1024
#define PKS_    (KVE_ + D_)   // 1056 floats: KV + Ksum
#define RPB_    32            // phase2: (n,l)-rows per block

__device__ __forceinline__ float phi_f(float x) {
    // elu(x)+1 : x>0 -> x+1 ; else exp(x)
    return x > 0.f ? x + 1.f : __expf(x);
}

// ---------------- Phase 1: KV + Ksum accumulation over s ----------------
template <bool ATOMIC>
__global__ __launch_bounds__(256) void la_phase1(
    const float* __restrict__ keys, const float* __restrict__ values,
    float* __restrict__ outp /* ATOMIC ? kvfinal[NH][PKS] : partials[NH][CHUNKS][PKS] */)
{
    __shared__ float kT[TILE_][D_];
    __shared__ float vT[TILE_][D_];
    const int nh    = blockIdx.x;   // 0..63
    const int chunk = blockIdx.y;   // 0..31
    const int n = nh >> 3, h = nh & 7;
    const int t  = threadIdx.x;
    const int d  = t & 31;          // this thread's K-dim
    const int vg = t >> 5;          // v-group: 4 consecutive v columns
    const size_t rs = (size_t)H_ * D_;   // 256 floats per (n,s) row
    const float* kbase = keys   + ((size_t)n * S_) * rs + (size_t)h * D_;
    const float* vbase = values + ((size_t)n * S_) * rs + (size_t)h * D_;
    const int s0 = chunk * ROWS_;

    float a0 = 0.f, a1 = 0.f, a2 = 0.f, a3 = 0.f, ksum = 0.f;

    for (int tb = 0; tb < ROWS_; tb += TILE_) {
        __syncthreads();
        // stage 64 rows of K (phi applied) and V; coalesced: 8 threads per row
#pragma unroll
        for (int i = 0; i < 2; ++i) {
            const int f   = t + i * 256;      // 0..511
            const int row = f >> 3;           // 0..63
            const int col = (f & 7) << 2;     // 0,4,...,28
            const size_t g = (size_t)(s0 + tb + row) * rs + col;
            const float4 k4 = *(const float4*)(kbase + g);
            const float4 v4 = *(const float4*)(vbase + g);
            *(float4*)&kT[row][col] =
                make_float4(phi_f(k4.x), phi_f(k4.y), phi_f(k4.z), phi_f(k4.w));
            *(float4*)&vT[row][col] = v4;
        }
        __syncthreads();
#pragma unroll 16
        for (int s = 0; s < TILE_; ++s) {
            const float  kk = kT[s][d];                        // b32, lanes->banks 0..31
            const float4 vv = *(const float4*)&vT[s][vg << 2]; // broadcast b128
            a0 = fmaf(kk, vv.x, a0);
            a1 = fmaf(kk, vv.y, a1);
            a2 = fmaf(kk, vv.z, a2);
            a3 = fmaf(kk, vv.w, a3);
            ksum += kk;   // identical across vg groups; only vg==0 stores it
        }
    }

    const int o = d * D_ + (vg << 2);
    if (ATOMIC) {
        float* p = outp + (size_t)nh * PKS_;
        atomicAdd(&p[o + 0], a0);
        atomicAdd(&p[o + 1], a1);
        atomicAdd(&p[o + 2], a2);
        atomicAdd(&p[o + 3], a3);
        if (vg == 0) atomicAdd(&p[KVE_ + d], ksum);
    } else {
        float* p = outp + ((size_t)nh * CHUNKS_ + chunk) * PKS_;
        *(float4*)&p[o] = make_float4(a0, a1, a2, a3);
        if (vg == 0) p[KVE_ + d] = ksum;
    }
}

// ---------------- Phase 1b: deterministic 32-way partial reduce ----------------
__global__ __launch_bounds__(256) void la_reduce(
    const float* __restrict__ partials, float* __restrict__ kvf)
{
    const int nh = blockIdx.x;
    for (int e = threadIdx.x; e < PKS_; e += 256) {
        const float* p = partials + (size_t)nh * CHUNKS_ * PKS_ + e;
        float s = 0.f;
#pragma unroll
        for (int c = 0; c < CHUNKS_; ++c) s += p[(size_t)c * PKS_];
        kvf[(size_t)nh * PKS_ + e] = s;
    }
}

__global__ void la_zero(float* __restrict__ p, int nelem) {
    const int i = blockIdx.x * 256 + threadIdx.x;
    if (i < nelem) p[i] = 0.f;
}

// ---------------- Phase 2: out = (phiQ . KV) * z ----------------
// Block = 32 consecutive (n,l) rows x ALL 8 heads. Wave w computes rows
// 8w..8w+7. Lane: h = lane>>3, vs = lane&7 (4 v-columns). Stores are 1KB
// dense per wave-instr; block writes 32KB contiguous.
__global__ __launch_bounds__(256, 2) void la_phase2(
    const float* __restrict__ queries, const float* __restrict__ kvf,
    float* __restrict__ out)
{
    __shared__ float4 qT[RPB_][65];   // [row][j*8+h], +1 float4 row pad
    const int t    = threadIdx.x;
    const int lane = t & 63;
    const int w    = t >> 6;          // wave id = row-group
    const int h    = lane >> 3;
    const int vs   = lane & 7;
    const size_t rowg0 = (size_t)blockIdx.x * RPB_;   // global (n,l)-row base
    const int n = (int)(rowg0 >> 13);                 // rowg0 / L_
    const float* kvbase = kvf + (size_t)(n * 8 + h) * PKS_;

    // ---- stage Q tile: 32 rows x 1KB contiguous; phi; transpose c4 -> j*8+h ----
    const float4* qg = (const float4*)(queries + rowg0 * 256);
#pragma unroll
    for (int i = 0; i < 8; ++i) {
        const int f   = t + i * 256;   // 0..2047 ; one full row per wave-instr
        const int row = f >> 6;
        const int c4  = f & 63;        // global float4 index in row = h*8 + j
        float4 q4 = qg[(size_t)row * 64 + c4];
        q4 = make_float4(phi_f(q4.x), phi_f(q4.y), phi_f(q4.z), phi_f(q4.w));
        qT[row][((c4 & 7) << 3) | (c4 >> 3)] = q4;   // [row][j*8+h]
    }

    // ---- KV[h] column slice (32 float4) + Ksum[h] (8 float4) -> VGPRs ----
    float4 kv[D_], ks[8];
#pragma unroll
    for (int dd = 0; dd < D_; ++dd)
        kv[dd] = *(const float4*)(kvbase + dd * D_ + (vs << 2));
#pragma unroll
    for (int j = 0; j < 8; ++j)
        ks[j] = *(const float4*)(kvbase + KVE_ + (j << 2));

    __syncthreads();

    float4* og = (float4*)(out + rowg0 * 256);
#pragma unroll
    for (int r = 0; r < 8; ++r) {
        const int row = (w << 3) + r;
        float dot = 0.f, a0 = 0.f, a1 = 0.f, a2 = 0.f, a3 = 0.f;
#pragma unroll
        for (int j = 0; j < 8; ++j) {
            const float4 q4 = qT[row][(j << 3) | h];   // broadcast, conflict-free
            dot = fmaf(q4.x, ks[j].x, dot);
            dot = fmaf(q4.y, ks[j].y, dot);
            dot = fmaf(q4.z, ks[j].z, dot);
            dot = fmaf(q4.w, ks[j].w, dot);
            const float4 k0 = kv[4 * j + 0], k1 = kv[4 * j + 1];
            const float4 k2 = kv[4 * j + 2], k3 = kv[4 * j + 3];
            a0 = fmaf(q4.x, k0.x, a0); a1 = fmaf(q4.x, k0.y, a1);
            a2 = fmaf(q4.x, k0.z, a2); a3 = fmaf(q4.x, k0.w, a3);
            a0 = fmaf(q4.y, k1.x, a0); a1 = fmaf(q4.y, k1.y, a1);
            a2 = fmaf(q4.y, k1.z, a2); a3 = fmaf(q4.y, k1.w, a3);
            a0 = fmaf(q4.z, k2.x, a0); a1 = fmaf(q4.z, k2.y, a1);
            a2 = fmaf(q4.z, k2.z, a2); a3 = fmaf(q4.z, k2.w, a3);
            a0 = fmaf(q4.w, k3.x, a0); a1 = fmaf(q4.w, k3.y, a1);
            a2 = fmaf(q4.w, k3.z, a2); a3 = fmaf(q4.w, k3.w, a3);
        }
        const float z = 1.f / (dot + 1e-6f);
        // wave-store: lanes 0..63 cover float4 0..63 of this row -> 1KB dense
        og[(size_t)row * 64 + lane] = make_float4(a0 * z, a1 * z, a2 * z, a3 * z);
    }
}

extern "C" void kernel_launch(void* const* d_in, const int* in_sizes, int n_in,
                              void* d_out, int out_size, void* d_ws, size_t ws_size,
                              hipStream_t stream)
{
    const float* queries = (const float*)d_in[0];
    const float* keys    = (const float*)d_in[1];
    const float* values  = (const float*)d_in[2];
    float* out = (float*)d_out;
    float* ws  = (float*)d_ws;

    const size_t partial_elems = (size_t)NH_ * CHUNKS_ * PKS_; // 2,162,688 floats
    const size_t final_elems   = (size_t)NH_ * PKS_;           // 67,584 floats
    const dim3 blk(256);
    const int p2_blocks = (N_ * L_) / RPB_;                    // 2048

    if (ws_size >= (partial_elems + final_elems) * sizeof(float)) {
        // deterministic two-stage reduction
        float* partials = ws;
        float* kvf      = ws + partial_elems;
        la_phase1<false><<<dim3(NH_, CHUNKS_), blk, 0, stream>>>(keys, values, partials);
        la_reduce<<<dim3(NH_), blk, 0, stream>>>(partials, kvf);
        la_phase2<<<dim3(p2_blocks), blk, 0, stream>>>(queries, kvf, out);
    } else {
        // fallback: atomic accumulation into zeroed final buffer
        float* kvf = ws;
        const int nz = (int)final_elems;
        la_zero<<<dim3((nz + 255) / 256), blk, 0, stream>>>(kvf, nz);
        la_phase1<true><<<dim3(NH_, CHUNKS_), blk, 0, stream>>>(keys, values, kvf);
        la_phase2<<<dim3(p2_blocks), blk, 0, stream>>>(queries, kvf, out);
    }
}